// Round 1
// baseline (1828.679 us; speedup 1.0000x reference)
//
#include <hip/hip_runtime.h>

// WindowAttention (Swin): x[4096,49,512] -> qkv GEMM -> per-window-head attention
// (rel-pos bias + shift mask + softmax) -> proj GEMM.
// Strategy: bf16 MFMA (16x16x32) for all matmul-shaped work, fp32 accumulate.
// ws layout (bytes):
//   [0)                qkv bf16      [200704][1536]   616,562,688
//   [616562688)        x_bf bf16     [200704][512]    205,520,896  (reused as attn_out)
//   [822083584)        WqkvT bf16    [1536][512]        1,572,864
//   [823656448)        WprojT bf16   [512][512]           524,288
//   [824180736)        biasmask f32  [64][16][49][49]   9,834,496
//   total 834,015,232

typedef short  v8s __attribute__((ext_vector_type(8)));
typedef float  v4f __attribute__((ext_vector_type(4)));

#define B_WIN 4096
#define S_TOK 49
#define DIM   512
#define NH    16
#define HD    32
#define NW    64
#define M_TOT (B_WIN * S_TOK)   // 200704

__device__ __forceinline__ unsigned short f2bfu(float f) {
    unsigned u = __builtin_bit_cast(unsigned, f);
    u += 0x7fffu + ((u >> 16) & 1u);   // RNE (inputs finite)
    return (unsigned short)(u >> 16);
}

// ---------------- prep kernels ----------------

__global__ void cvt_x_kernel(const float4* __restrict__ x, ushort4* __restrict__ xb, int n4) {
    int i = blockIdx.x * 256 + threadIdx.x;
    if (i < n4) {
        float4 v = x[i];
        ushort4 o;
        o.x = f2bfu(v.x); o.y = f2bfu(v.y); o.z = f2bfu(v.z); o.w = f2bfu(v.w);
        xb[i] = o;
    }
}

// W [K][N] (f32, row-major) -> Wt [N][K] (bf16)
__global__ void cvt_wt_kernel(const float* __restrict__ W, unsigned short* __restrict__ Wt,
                              int K, int N) {
    int idx = blockIdx.x * 256 + threadIdx.x;
    if (idx >= N * K) return;
    int n = idx / K, k = idx - n * K;
    Wt[idx] = f2bfu(W[(size_t)k * N + n]);
}

// bm[(g*16+h)*2401 + i*49 + j] = bias_table[rel[i*49+j]*16 + h] + mask[g*2401 + i*49 + j]
__global__ void build_bm_kernel(const float* __restrict__ bias_table,
                                const int* __restrict__ rel_index,
                                const float* __restrict__ mask,
                                float* __restrict__ bm) {
    int idx = blockIdx.x * 256 + threadIdx.x;  // 64*16*2401 = 2,458,624 exact
    int ij = idx % 2401;
    int gh = idx / 2401;
    int h = gh & 15, g = gh >> 4;
    bm[idx] = bias_table[rel_index[ij] * NH + h] + mask[g * 2401 + ij];
}

// ---------------- GEMM: C[M][N] = A[M][K] @ Bt[N][K]^T + bias ----------------
// 128x128 tile, BK=32, 256 threads (4 waves, each 64x64), global_load_lds(16B).
template <int OUT_BF16>
__global__ __launch_bounds__(256) void gemm_bt(
    const unsigned short* __restrict__ A,   // [M][K] bf16
    const unsigned short* __restrict__ Bt,  // [N][K] bf16
    const float* __restrict__ bias,         // [N]
    void* __restrict__ Cout,                // [M][N] bf16 or f32
    int M, int N, int K) {
    __shared__ unsigned short As[128 * 32];  // row-major [m][k], 8 KB
    __shared__ unsigned short Bs[128 * 32];  // row-major [n][k], 8 KB
    const int tid  = threadIdx.x;
    const int wave = tid >> 6;
    const int lane = tid & 63;
    const int r    = lane & 15;
    const int quad = lane >> 4;
    const int m0 = blockIdx.y * 128;
    const int n0 = blockIdx.x * 128;
    const int woffm = (wave >> 1) * 64;
    const int woffn = (wave & 1) * 64;

    const char* gA = (const char*)(A + (size_t)m0 * K);
    const char* gB = (const char*)(Bt + (size_t)n0 * K);
    char* lA = (char*)As;
    char* lB = (char*)Bs;
    const int c0 = wave * 2;

    v4f acc[4][4] = {};

    for (int k0 = 0; k0 < K; k0 += 32) {
        __syncthreads();  // previous iteration's ds_reads done before overwrite
#pragma unroll
        for (int hh = 0; hh < 2; ++hh) {
            int f   = (c0 + hh) * 1024 + lane * 16;  // flat LDS byte offset
            int row = f >> 6;                        // 64 B per row (32 bf16)
            int kb  = f & 63;
            __builtin_amdgcn_global_load_lds(
                (const __attribute__((address_space(1))) unsigned int*)(gA + (size_t)row * (K * 2) + k0 * 2 + kb),
                (__attribute__((address_space(3))) unsigned int*)(lA + f), 16, 0, 0);
            __builtin_amdgcn_global_load_lds(
                (const __attribute__((address_space(1))) unsigned int*)(gB + (size_t)row * (K * 2) + k0 * 2 + kb),
                (__attribute__((address_space(3))) unsigned int*)(lB + f), 16, 0, 0);
        }
        __syncthreads();  // drains vmcnt: staged data visible

        v8s af[4], bfr[4];
#pragma unroll
        for (int t = 0; t < 4; ++t)
            af[t] = *(const v8s*)(lA + ((woffm + 16 * t + r) * 32 + quad * 8) * 2);
#pragma unroll
        for (int t = 0; t < 4; ++t)
            bfr[t] = *(const v8s*)(lB + ((woffn + 16 * t + r) * 32 + quad * 8) * 2);
#pragma unroll
        for (int i = 0; i < 4; ++i)
#pragma unroll
            for (int j = 0; j < 4; ++j)
                acc[i][j] = __builtin_amdgcn_mfma_f32_16x16x32_bf16(af[i], bfr[j], acc[i][j], 0, 0, 0);
    }

#pragma unroll
    for (int j = 0; j < 4; ++j) {
        int n = n0 + woffn + 16 * j + r;
        float bv = bias[n];
#pragma unroll
        for (int i = 0; i < 4; ++i) {
#pragma unroll
            for (int rg = 0; rg < 4; ++rg) {
                int m = m0 + woffm + 16 * i + quad * 4 + rg;
                float val = acc[i][j][rg] + bv;
                if (OUT_BF16)
                    ((unsigned short*)Cout)[(size_t)m * N + n] = f2bfu(val);
                else
                    ((float*)Cout)[(size_t)m * N + n] = val;
            }
        }
    }
}

// ---------------- attention: one wave per (window, head) ----------------
// scores = (q@k^T)*scale + bm  (64x64 padded; 16 MFMAs), in-register softmax,
// P -> LDS (A-layout), V -> LDS transposed, out = P@V (16 MFMAs).
__global__ __launch_bounds__(256) void attn_kernel(
    const unsigned short* __restrict__ qkv,  // [200704][1536] bf16
    const float* __restrict__ bm,            // [64][16][49][49]
    unsigned short* __restrict__ out) {      // [200704][512] bf16
    const int w    = blockIdx.x;
    const int wave = threadIdx.x >> 6;
    const int h    = blockIdx.y * 4 + wave;
    const int lane = threadIdx.x & 63;
    const int r    = lane & 15;
    const int quad = lane >> 4;
    const int g    = w & (NW - 1);
    const size_t base = (size_t)w * S_TOK;

    __shared__ unsigned short pbuf[4][64 * 72];  // 36,864 B (stride 72: 144B rows, 16B-aligned)
    __shared__ unsigned short vbuf[4][32 * 72];  // 18,432 B
    unsigned short* p_lds = pbuf[wave];
    unsigned short* vt    = vbuf[wave];

    // ---- stage V transposed: vt[d][j] = v[j][d], zero-pad j in [49,64) ----
    {
        int j = lane;
        union { uint4 q[4]; unsigned short s[32]; } vv;
        if (j < S_TOK) {
            const uint4* vrow = (const uint4*)(qkv + (base + j) * 1536 + 1024 + (size_t)h * HD);
#pragma unroll
            for (int c = 0; c < 4; ++c) vv.q[c] = vrow[c];
        } else {
#pragma unroll
            for (int c = 0; c < 4; ++c) vv.q[c] = make_uint4(0, 0, 0, 0);
        }
#pragma unroll
        for (int d = 0; d < HD; ++d) vt[d * 72 + j] = vv.s[d];
    }

    // ---- load Q/K fragments (A-layout: row=lane&15, k=quad*8..+7), zero-pad ----
    v8s zf = {0, 0, 0, 0, 0, 0, 0, 0};
    v8s aq[4], bk[4];
#pragma unroll
    for (int t = 0; t < 4; ++t) {
        int row = 16 * t + r;
        if (row < S_TOK) {
            const unsigned short* qp = qkv + (base + row) * 1536 + (size_t)h * HD + quad * 8;
            aq[t] = *(const v8s*)qp;
            bk[t] = *(const v8s*)(qp + 512);
        } else {
            aq[t] = zf;
            bk[t] = zf;
        }
    }

    // ---- scores ----
    v4f sc[4][4] = {};
#pragma unroll
    for (int i = 0; i < 4; ++i)
#pragma unroll
        for (int j = 0; j < 4; ++j)
            sc[i][j] = __builtin_amdgcn_mfma_f32_16x16x32_bf16(aq[i], bk[j], sc[i][j], 0, 0, 0);

    // ---- scale + bias/mask + row softmax (rows live in 16-lane quads) ----
    const float scale = 0.17677669529663687f;  // 32^-0.5
    const float* bmh = bm + (size_t)(g * NH + h) * 2401;
#pragma unroll
    for (int it = 0; it < 4; ++it) {
#pragma unroll
        for (int rg = 0; rg < 4; ++rg) {
            int i = 16 * it + quad * 4 + rg;
            float s[4];
#pragma unroll
            for (int jt = 0; jt < 4; ++jt) {
                int j = 16 * jt + r;
                float v = sc[it][jt][rg] * scale;
                if (i < S_TOK && j < S_TOK) v += bmh[i * 49 + j];
                if (j >= S_TOK) v = -1e30f;
                s[jt] = v;
            }
            float mx = fmaxf(fmaxf(s[0], s[1]), fmaxf(s[2], s[3]));
#pragma unroll
            for (int d = 1; d < 16; d <<= 1) mx = fmaxf(mx, __shfl_xor(mx, d));
            float sum = 0.f;
#pragma unroll
            for (int jt = 0; jt < 4; ++jt) { s[jt] = __expf(s[jt] - mx); sum += s[jt]; }
#pragma unroll
            for (int d = 1; d < 16; d <<= 1) sum += __shfl_xor(sum, d);
            float inv = 1.0f / sum;
#pragma unroll
            for (int jt = 0; jt < 4; ++jt) sc[it][jt][rg] = s[jt] * inv;
        }
    }

    // ---- P (C-layout) -> LDS row-major [i][j] for A-layout reads ----
#pragma unroll
    for (int it = 0; it < 4; ++it)
#pragma unroll
        for (int jt = 0; jt < 4; ++jt)
#pragma unroll
            for (int rg = 0; rg < 4; ++rg) {
                int i = 16 * it + quad * 4 + rg;
                int j = 16 * jt + r;
                p_lds[i * 72 + j] = f2bfu(sc[it][jt][rg]);
            }

    __syncthreads();  // lgkm drain: p_lds/vt writes visible to own ds_reads

    // ---- out = P @ V : M=64(i), K=64(j), N=32(d) ----
    v4f oacc[4][2] = {};
#pragma unroll
    for (int kt = 0; kt < 2; ++kt) {
        v8s bv[2];
#pragma unroll
        for (int nt = 0; nt < 2; ++nt)
            bv[nt] = *(const v8s*)(vt + (16 * nt + r) * 72 + 32 * kt + quad * 8);
#pragma unroll
        for (int it = 0; it < 4; ++it) {
            v8s ap = *(const v8s*)(p_lds + (16 * it + r) * 72 + 32 * kt + quad * 8);
#pragma unroll
            for (int nt = 0; nt < 2; ++nt)
                oacc[it][nt] = __builtin_amdgcn_mfma_f32_16x16x32_bf16(ap, bv[nt], oacc[it][nt], 0, 0, 0);
        }
    }

    // ---- store attn_out bf16 [m][512] at col h*32 ----
#pragma unroll
    for (int it = 0; it < 4; ++it)
#pragma unroll
        for (int nt = 0; nt < 2; ++nt)
#pragma unroll
            for (int rg = 0; rg < 4; ++rg) {
                int i = 16 * it + quad * 4 + rg;
                if (i < S_TOK)
                    out[(base + i) * DIM + h * HD + 16 * nt + r] = f2bfu(oacc[it][nt][rg]);
            }
}

// ---------------- launch ----------------

extern "C" void kernel_launch(void* const* d_in, const int* in_sizes, int n_in,
                              void* d_out, int out_size, void* d_ws, size_t ws_size,
                              hipStream_t stream) {
    const float* x          = (const float*)d_in[0];
    const float* mask       = (const float*)d_in[1];
    const float* Wqkv       = (const float*)d_in[2];
    const float* bqkv       = (const float*)d_in[3];
    const float* Wproj      = (const float*)d_in[4];
    const float* bproj      = (const float*)d_in[5];
    const float* bias_table = (const float*)d_in[6];
    const int*   rel_index  = (const int*)d_in[7];
    float* out = (float*)d_out;

    char* ws = (char*)d_ws;
    unsigned short* qkv    = (unsigned short*)(ws);                  // 616,562,688
    unsigned short* xbf    = (unsigned short*)(ws + 616562688);      // 205,520,896 (→ attn_out)
    unsigned short* wqkvt  = (unsigned short*)(ws + 822083584);      // 1,572,864
    unsigned short* wprojt = (unsigned short*)(ws + 823656448);      // 524,288
    float*          bm     = (float*)(ws + 824180736);               // 9,834,496

    // prep
    cvt_x_kernel<<<100352, 256, 0, stream>>>((const float4*)x, (ushort4*)xbf, 25690112);
    cvt_wt_kernel<<<(1536 * 512) / 256, 256, 0, stream>>>(Wqkv, wqkvt, 512, 1536);
    cvt_wt_kernel<<<(512 * 512) / 256, 256, 0, stream>>>(Wproj, wprojt, 512, 512);
    build_bm_kernel<<<(NW * NH * 2401) / 256, 256, 0, stream>>>(bias_table, rel_index, mask, bm);

    // qkv = x @ Wqkv + bqkv   (M=200704, N=1536, K=512) -> bf16
    gemm_bt<1><<<dim3(12, 1568), 256, 0, stream>>>(xbf, wqkvt, bqkv, qkv, M_TOT, 1536, 512);

    // attention -> attn_out (aliases xbf; x_bf is dead after the qkv GEMM)
    attn_kernel<<<dim3(B_WIN, 4), 256, 0, stream>>>(qkv, bm, xbf);

    // out = attn_out @ Wproj + bproj  (M=200704, N=512, K=512) -> f32
    gemm_bt<0><<<dim3(4, 1568), 256, 0, stream>>>(xbf, wprojt, bproj, out, M_TOT, 512, 512);
}